// Round 17
// baseline (114.337 us; speedup 1.0000x reference)
//
#include <hip/hip_runtime.h>

// 2-layer GRU, B=131072, T=24, H=8. MFMA formulation (math verified r8).
// Round-17: BATCHED RCP. Model (fits r8-r16 data at 91%): single shared
// VALU resource, trans ops = 16 cyc/wave, VALU = 2 cyc. Step cost
// 4x(48*16 + 115*2) = 3992 cyc ~ measured 4400. Only lever: fewer trans.
// Montgomery product-tree: 4 reciprocals from 1 v_rcp + 9 muls (exact to
// ~ulp). Per wave-step trans 48->30. Base = r14 rolled kernel (44.8us).

typedef __fp16 h2f    __attribute__((ext_vector_type(2)));
typedef __fp16 half8  __attribute__((ext_vector_type(8)));
typedef float  f32x16 __attribute__((ext_vector_type(16)));

#define LOG2E 1.44269504088896f

__device__ __forceinline__ h2f pk2f(float a, float b) {
  return __builtin_amdgcn_cvt_pkrtz(a, b);
}

union H8U { half8 h; unsigned u[4]; h2f p[4]; };

// lanes<32 receive x from lane+32; lanes>=32 keep a don't-care copy
// (A-frag rows k=8..15 are zero, so B content there never contributes).
__device__ __forceinline__ unsigned from_upper(unsigned x) {
  auto r = __builtin_amdgcn_permlane32_swap((int)x, (int)x, false, false);
  return (unsigned)r[1];
}

// 4 reciprocals from one v_rcp (Montgomery product tree). Exact to ~1 ulp
// per result; inputs here are 1+2^x in [1, 2^16] so no overflow.
__device__ __forceinline__ void rcp4(float a0, float a1, float a2, float a3,
                                     float& r0, float& r1, float& r2, float& r3) {
  const float p1 = a0 * a1;
  const float p2 = p1 * a2;
  const float p3 = p2 * a3;
  const float R  = __builtin_amdgcn_rcpf(p3);   // 1/(a0 a1 a2 a3)
  r3 = R * p2;                                  // 1/a3
  const float Rb = R * a3;                      // 1/(a0 a1 a2)
  r2 = Rb * p1;                                 // 1/a2
  const float Rc = Rb * a2;                     // 1/(a0 a1)
  r1 = Rc * a0;                                 // 1/a1
  r0 = Rc * a1;                                 // 1/a0
}

#define MFMA_(A, B, C) __builtin_amdgcn_mfma_f32_32x32x16_f16((A), (B), (C), 0, 0, 0)

__global__ __launch_bounds__(256, 4) void gru2_mfma(
    const int* __restrict__ inputs,
    const float* __restrict__ emb,
    const float* __restrict__ w_ih1, const float* __restrict__ w_hh1,
    const float* __restrict__ b_ih1, const float* __restrict__ b_hh1,
    const float* __restrict__ w_ih2, const float* __restrict__ w_hh2,
    const float* __restrict__ b_ih2, const float* __restrict__ b_hh2,
    float* __restrict__ out)
{
  __shared__ float G1f[27 * 33];   // [token][gate], odd stride: token->bank bijective
  __shared__ int   TK[128 * 25];

  const int tid   = threadIdx.x;
  const int lane  = tid & 63;
  const int wid   = tid >> 6;
  const int half_ = lane >> 5;
  const int col   = lane & 31;

  // ---- G1 table: scaled input-side gates for all 27 tokens ----
  for (int idx = tid; idx < 27 * 24; idx += 256) {
    const int tok = idx / 24, g = idx - tok * 24;
    const float s = (g < 16) ? -LOG2E : 2.f * LOG2E;
    float a = b_ih1[g] + ((g < 16) ? b_hh1[g] : 0.f);
    if (tok != 0) {
      #pragma unroll
      for (int j = 0; j < 8; ++j) a = fmaf(w_ih1[g * 8 + j], emb[tok * 8 + j], a);
    }
    G1f[tok * 33 + g] = s * a;
  }

  // ---- stage this block's 128x24 tokens, coalesced ----
  const long gbase = (long)blockIdx.x * (128 * 24);
  #pragma unroll
  for (int k = 0; k < 12; ++k) {
    const int i = tid + k * 256;
    TK[(i / 24) * 25 + (i % 24)] = inputs[gbase + i];
  }
  __syncthreads();

  const int sl = wid * 32 + col;
  unsigned pkw[4] = {0u, 0u, 0u, 0u};
  #pragma unroll
  for (int t = 0; t < 24; ++t)
    pkw[t / 6] |= ((unsigned)TK[sl * 25 + t]) << (5 * (t % 6));
  const unsigned pk0 = pkw[0], pk1 = pkw[1], pk2_ = pkw[2], pk3 = pkw[3];

  // ---- weight A-frags (lane<32: row=col of W, k=0..7 scaled; else zero) ----
  auto loadW = [&](const float* w) -> half8 {
    H8U u;
    u.u[0] = u.u[1] = u.u[2] = u.u[3] = 0u;
    if (half_ == 0 && col < 24) {
      const float s = (col < 16) ? -LOG2E : 2.f * LOG2E;
      const float4* p = (const float4*)(w + col * 8);
      const float4 x = p[0], y = p[1];
      u.p[0] = pk2f(x.x * s, x.y * s);
      u.p[1] = pk2f(x.z * s, x.w * s);
      u.p[2] = pk2f(y.x * s, y.y * s);
      u.p[3] = pk2f(y.z * s, y.w * s);
    }
    return u.h;
  };
  const half8 wa1  = loadW(w_hh1);
  const half8 wa2i = loadW(w_ih2);
  const half8 wa2h = loadW(w_hh2);

  // ---- layer-2 bias C-frag ----
  f32x16 c2;
  #pragma unroll
  for (int r = 0; r < 16; ++r) {
    const int m = (r & 3) + 8 * (r >> 2) + 4 * half_;
    float v;
    if (m < 16)      v = -LOG2E * (b_ih2[m] + b_hh2[m]);
    else if (m < 24) v = 2.f * LOG2E * b_hh2[m];
    else             v = 0.f;
    c2[r] = v;
  }
  float bn1[4], bi2n[4];
  #pragma unroll
  for (int i = 0; i < 4; ++i) {
    bn1[i]  = 2.f * LOG2E * b_hh1[16 + 4 * half_ + i];
    bi2n[i] = 2.f * LOG2E * b_ih2[16 + 4 * half_ + i];
  }

  float h1v[4] = {0.f, 0.f, 0.f, 0.f}, h2v[4] = {0.f, 0.f, 0.f, 0.f};
  H8U f1, f2;
  f1.u[0] = f1.u[1] = f1.u[2] = f1.u[3] = 0u;
  f2 = f1;

  const float* g1base = G1f + half_ * 4;

  // ---- rolled time loop: 4 outer iterations x 6 unrolled steps ----
  for (int t6 = 0; t6 < 4; ++t6) {
    const unsigned pw = (t6 == 0) ? pk0 : (t6 == 1) ? pk1 : (t6 == 2) ? pk2_ : pk3;

    #pragma unroll
    for (int j = 0; j < 6; ++j) {
      const unsigned tok = (pw >> (5 * j)) & 31u;
      const float* gp = g1base + tok * 33;

      f32x16 c1;
      c1[0] = gp[0];  c1[1] = gp[1];  c1[2] = gp[2];  c1[3] = gp[3];
      c1[4] = gp[8];  c1[5] = gp[9];  c1[6] = gp[10]; c1[7] = gp[11];
      c1[8] = bn1[0]; c1[9] = bn1[1]; c1[10] = bn1[2]; c1[11] = bn1[3];
      c1[12] = 0.f; c1[13] = 0.f; c1[14] = 0.f; c1[15] = 0.f;

      const f32x16 dh = MFMA_(wa2h, f2.h, c2);     // L2 recurrent (independent)
      const f32x16 d1 = MFMA_(wa1, f1.h, c1);      // L1 full gates

      // ---- layer-1 cell, batched rcp (3 v_rcp instead of 12) ----
      {
        const float ar0 = 1.f + __builtin_amdgcn_exp2f(d1[0]);
        const float ar1 = 1.f + __builtin_amdgcn_exp2f(d1[1]);
        const float ar2 = 1.f + __builtin_amdgcn_exp2f(d1[2]);
        const float ar3 = 1.f + __builtin_amdgcn_exp2f(d1[3]);
        float r0, r1, r2, r3;
        rcp4(ar0, ar1, ar2, ar3, r0, r1, r2, r3);

        const float az0 = 1.f + __builtin_amdgcn_exp2f(d1[4]);
        const float az1 = 1.f + __builtin_amdgcn_exp2f(d1[5]);
        const float az2 = 1.f + __builtin_amdgcn_exp2f(d1[6]);
        const float az3 = 1.f + __builtin_amdgcn_exp2f(d1[7]);
        float z0, z1, z2, z3;
        rcp4(az0, az1, az2, az3, z0, z1, z2, z3);

        const float an0 = 1.f + __builtin_amdgcn_exp2f(fmaf(r0, d1[8],  gp[16]));
        const float an1 = 1.f + __builtin_amdgcn_exp2f(fmaf(r1, d1[9],  gp[17]));
        const float an2 = 1.f + __builtin_amdgcn_exp2f(fmaf(r2, d1[10], gp[18]));
        const float an3 = 1.f + __builtin_amdgcn_exp2f(fmaf(r3, d1[11], gp[19]));
        float i0, i1, i2, i3;
        rcp4(an0, an1, an2, an3, i0, i1, i2, i3);

        const float n0 = fmaf(-2.f, i0, 1.f);
        const float n1 = fmaf(-2.f, i1, 1.f);
        const float n2 = fmaf(-2.f, i2, 1.f);
        const float n3 = fmaf(-2.f, i3, 1.f);
        h1v[0] = n0 + z0 * (h1v[0] - n0);
        h1v[1] = n1 + z1 * (h1v[1] - n1);
        h1v[2] = n2 + z2 * (h1v[2] - n2);
        h1v[3] = n3 + z3 * (h1v[3] - n3);
      }
      {
        const unsigned a = __builtin_bit_cast(unsigned, pk2f(h1v[0], h1v[1]));
        const unsigned b = __builtin_bit_cast(unsigned, pk2f(h1v[2], h1v[3]));
        f1.u[0] = a; f1.u[1] = b;
        f1.u[2] = from_upper(a); f1.u[3] = from_upper(b);
      }

      const f32x16 dg = MFMA_(wa2i, f1.h, dh);     // L2 input gates, chained C

      // ---- layer-2 cell, batched rcp ----
      {
        const float ar0 = 1.f + __builtin_amdgcn_exp2f(dg[0]);
        const float ar1 = 1.f + __builtin_amdgcn_exp2f(dg[1]);
        const float ar2 = 1.f + __builtin_amdgcn_exp2f(dg[2]);
        const float ar3 = 1.f + __builtin_amdgcn_exp2f(dg[3]);
        float r0, r1, r2, r3;
        rcp4(ar0, ar1, ar2, ar3, r0, r1, r2, r3);

        const float az0 = 1.f + __builtin_amdgcn_exp2f(dg[4]);
        const float az1 = 1.f + __builtin_amdgcn_exp2f(dg[5]);
        const float az2 = 1.f + __builtin_amdgcn_exp2f(dg[6]);
        const float az3 = 1.f + __builtin_amdgcn_exp2f(dg[7]);
        float z0, z1, z2, z3;
        rcp4(az0, az1, az2, az3, z0, z1, z2, z3);

        const float gin0 = dg[8]  - dh[8]  + bi2n[0];
        const float gin1 = dg[9]  - dh[9]  + bi2n[1];
        const float gin2 = dg[10] - dh[10] + bi2n[2];
        const float gin3 = dg[11] - dh[11] + bi2n[3];
        const float an0 = 1.f + __builtin_amdgcn_exp2f(fmaf(r0, dh[8],  gin0));
        const float an1 = 1.f + __builtin_amdgcn_exp2f(fmaf(r1, dh[9],  gin1));
        const float an2 = 1.f + __builtin_amdgcn_exp2f(fmaf(r2, dh[10], gin2));
        const float an3 = 1.f + __builtin_amdgcn_exp2f(fmaf(r3, dh[11], gin3));
        float i0, i1, i2, i3;
        rcp4(an0, an1, an2, an3, i0, i1, i2, i3);

        const float n0 = fmaf(-2.f, i0, 1.f);
        const float n1 = fmaf(-2.f, i1, 1.f);
        const float n2 = fmaf(-2.f, i2, 1.f);
        const float n3 = fmaf(-2.f, i3, 1.f);
        h2v[0] = n0 + z0 * (h2v[0] - n0);
        h2v[1] = n1 + z1 * (h2v[1] - n1);
        h2v[2] = n2 + z2 * (h2v[2] - n2);
        h2v[3] = n3 + z3 * (h2v[3] - n3);
      }
      {
        const unsigned a = __builtin_bit_cast(unsigned, pk2f(h2v[0], h2v[1]));
        const unsigned b = __builtin_bit_cast(unsigned, pk2f(h2v[2], h2v[3]));
        f2.u[0] = a; f2.u[1] = b;
        f2.u[2] = from_upper(a); f2.u[3] = from_upper(b);
      }
    }
  }

  const long seq = (long)blockIdx.x * 128 + sl;
  *(float4*)(out + seq * 8 + 4 * half_) =
      make_float4(h2v[0], h2v[1], h2v[2], h2v[3]);
}

extern "C" void kernel_launch(void* const* d_in, const int* in_sizes, int n_in,
                              void* d_out, int out_size, void* d_ws, size_t ws_size,
                              hipStream_t stream) {
  const int*   inputs = (const int*)d_in[0];
  const float* emb    = (const float*)d_in[1];
  const float* w_ih1  = (const float*)d_in[2];
  const float* w_hh1  = (const float*)d_in[3];
  const float* b_ih1  = (const float*)d_in[4];
  const float* b_hh1  = (const float*)d_in[5];
  const float* w_ih2  = (const float*)d_in[6];
  const float* w_hh2  = (const float*)d_in[7];
  const float* b_ih2  = (const float*)d_in[8];
  const float* b_hh2  = (const float*)d_in[9];
  float* out = (float*)d_out;

  const int B = in_sizes[0] / 24;        // 131072
  const int grid = B / 128;              // 1024 blocks, 4 waves/SIMD

  hipLaunchKernelGGL(gru2_mfma, dim3(grid), dim3(256), 0, stream,
                     inputs, emb, w_ih1, w_hh1, b_ih1, b_hh1,
                     w_ih2, w_hh2, b_ih2, b_hh2, out);
}